// Round 3
// baseline (277.834 us; speedup 1.0000x reference)
//
#include <hip/hip_runtime.h>

#define BB 4
#define HH 8
#define SS 2048
#define DD 32
#define DMODEL 256
#define NEG_BIG_F (-1000000000.0f)
#define SCALE 0.17677669529663687f

typedef short short8 __attribute__((ext_vector_type(8)));
typedef float float4_ __attribute__((ext_vector_type(4)));

__device__ __forceinline__ unsigned short f2bf(float x) {
  unsigned u = __float_as_uint(x);
  u += 0x7FFFu + ((u >> 16) & 1u);
  return (unsigned short)(u >> 16);
}

// ---------- Kernel 0: transpose+bf16 all weights: Wt[z][n][k] -------------
__global__ __launch_bounds__(256) void prep_w(
    const float* __restrict__ Wq, const float* __restrict__ Wk,
    const float* __restrict__ Wv, const float* __restrict__ Wo,
    unsigned short* __restrict__ wt) {
  __shared__ float tile[32][33];
  int z = blockIdx.z;
  const float* W = (z == 0) ? Wq : (z == 1) ? Wk : (z == 2) ? Wv : Wo;
  unsigned short* dst = wt + (size_t)z * DMODEL * DMODEL;
  int k0 = blockIdx.x * 32, n0 = blockIdx.y * 32;
  int tx = threadIdx.x & 31, ty = threadIdx.x >> 5;  // (32,8)
  for (int r = ty; r < 32; r += 8)
    tile[r][tx] = W[(size_t)(k0 + r) * DMODEL + n0 + tx];
  __syncthreads();
  for (int r = ty; r < 32; r += 8)
    dst[(size_t)(n0 + r) * DMODEL + k0 + tx] = f2bf(tile[tx][r]);
}

// ---------- Kernel 1: fused Q/K/V projections -> bf16, head-split ---------
// qh/kh/vh layout: [b][h][s][d], d contiguous (32 bf16 = 64B rows)
__global__ __launch_bounds__(256) void proj_kernel(
    const float* __restrict__ q, const float* __restrict__ k,
    const float* __restrict__ v, const unsigned short* __restrict__ wt,
    unsigned short* __restrict__ qh, unsigned short* __restrict__ kh,
    unsigned short* __restrict__ vh) {
  int z = blockIdx.z;
  const float* src = (z == 0) ? q : (z == 1) ? k : v;
  const unsigned short* Wt = wt + (size_t)z * DMODEL * DMODEL;  // [n][k]
  unsigned short* dst = (z == 0) ? qh : (z == 1) ? kh : vh;

  int w = threadIdx.x >> 6, lane = threadIdx.x & 63, l16 = lane & 15,
      g = lane >> 4;
  int row = blockIdx.x * 64 + w * 16 + l16;
  int n0 = blockIdx.y * 64;

  float4_ z4 = {0.f, 0.f, 0.f, 0.f};
  float4_ acc[4] = {z4, z4, z4, z4};

  for (int k0 = 0; k0 < DMODEL; k0 += 32) {
    const float4_* ap = (const float4_*)(src + (size_t)row * DMODEL + k0 + 8 * g);
    float4_ a0 = ap[0], a1 = ap[1];
    short8 a;
#pragma unroll
    for (int j = 0; j < 4; ++j) {
      a[j] = (short)f2bf(a0[j]);
      a[4 + j] = (short)f2bf(a1[j]);
    }
#pragma unroll
    for (int cb = 0; cb < 4; ++cb) {
      int n = n0 + cb * 16 + l16;
      short8 bfr = *(const short8*)(Wt + (size_t)n * DMODEL + k0 + 8 * g);
      acc[cb] = __builtin_amdgcn_mfma_f32_16x16x32_bf16(a, bfr, acc[cb], 0, 0, 0);
    }
  }

  int rowbase = blockIdx.x * 64 + w * 16 + 4 * g;
#pragma unroll
  for (int cb = 0; cb < 4; ++cb) {
#pragma unroll
    for (int rr = 0; rr < 4; ++rr) {
      int r = rowbase + rr;
      int c = n0 + cb * 16 + l16;
      int b = r >> 11, s = r & (SS - 1);
      int h = c >> 5, d = c & 31;
      dst[(((size_t)(b * HH + h) * SS + s) * DD) + d] = f2bf(acc[cb][rr]);
    }
  }
}

// ---------- Kernel 2: fused stats + emit attn + PV ctx --------------------
__global__ __launch_bounds__(256) void fused_attn(
    const unsigned short* __restrict__ qh, const unsigned short* __restrict__ kh,
    const unsigned short* __restrict__ vh, const float* __restrict__ mask,
    float* __restrict__ attn_out, unsigned short* __restrict__ concat) {
  __shared__ float bias[SS];
  __shared__ unsigned short vt[32][72];     // V^T tile, +8 pad
  __shared__ unsigned short at[4][16][72];  // per-wave P tile [16 q][64 k]+pad

  int bh = blockIdx.y;
  int b = bh >> 3, h = bh & 7;
  for (int i = threadIdx.x; i < SS; i += 256)
    bias[i] = (1.0f - mask[(size_t)b * SS + i]) * NEG_BIG_F;
  __syncthreads();

  int w = threadIdx.x >> 6, lane = threadIdx.x & 63, l16 = lane & 15,
      g = lane >> 4;
  int q0 = blockIdx.x * 64 + w * 16;

  short8 qa = *(const short8*)(qh + ((size_t)bh * SS + q0 + l16) * DD + 8 * g);

  const unsigned short* kbase = kh + (size_t)bh * SS * DD;
  const unsigned short* vbase = vh + (size_t)bh * SS * DD;
  float4_ z4 = {0.f, 0.f, 0.f, 0.f};

  // ---- pass 1: online m/l (branchy: 1 exp per element on common path) ----
  float m[4], l[4];
#pragma unroll
  for (int i = 0; i < 4; ++i) {
    m[i] = -INFINITY;
    l[i] = 0.f;
  }
#pragma unroll 2
  for (int k0 = 0; k0 < SS; k0 += 16) {
    short8 kf = *(const short8*)(kbase + (size_t)(k0 + l16) * DD + 8 * g);
    float4_ r = __builtin_amdgcn_mfma_f32_16x16x32_bf16(qa, kf, z4, 0, 0, 0);
    float bk = bias[k0 + l16];
#pragma unroll
    for (int rr = 0; rr < 4; ++rr) {
      float t = fmaf(r[rr], SCALE, bk);
      if (t > m[rr]) {
        l[rr] = l[rr] * __expf(m[rr] - t) + 1.0f;
        m[rr] = t;
      } else {
        l[rr] += __expf(t - m[rr]);
      }
    }
  }
  // merge across the 16 k-lanes of each g-group (m finite here)
#pragma unroll
  for (int off = 1; off < 16; off <<= 1) {
#pragma unroll
    for (int rr = 0; rr < 4; ++rr) {
      float om = __shfl_xor(m[rr], off);
      float ol = __shfl_xor(l[rr], off);
      if (om > m[rr]) {
        l[rr] = l[rr] * __expf(m[rr] - om) + ol;
        m[rr] = om;
      } else {
        l[rr] += ol * __expf(om - m[rr]);
      }
    }
  }
  float rl[4];
#pragma unroll
  for (int rr = 0; rr < 4; ++rr) rl[rr] = 1.0f / l[rr];

  // ---- pass 2: emit normalized attn (write-once, nontemporal) + PV ------
  float* arow = attn_out + (size_t)bh * SS * SS;
  float4_ acc0 = z4, acc1 = z4;

  int vr = threadIdx.x >> 2;         // 0..63: v-row in tile
  int dseg = (threadIdx.x & 3) * 8;  // d start

  for (int kb = 0; kb < SS; kb += 64) {
    __syncthreads();
    {  // stage V^T
      short8 vv = *(const short8*)(vbase + (size_t)(kb + vr) * DD + dseg);
#pragma unroll
      for (int j = 0; j < 8; ++j) vt[dseg + j][vr] = (unsigned short)vv[j];
    }
    __syncthreads();

#pragma unroll
    for (int ks = 0; ks < 2; ++ks) {
#pragma unroll
      for (int kt = 0; kt < 2; ++kt) {
        int k0 = kb + ks * 32 + kt * 16;
        short8 kf = *(const short8*)(kbase + (size_t)(k0 + l16) * DD + 8 * g);
        float4_ r = __builtin_amdgcn_mfma_f32_16x16x32_bf16(qa, kf, z4, 0, 0, 0);
        float bk = bias[k0 + l16];
#pragma unroll
        for (int rr = 0; rr < 4; ++rr) {
          float t = fmaf(r[rr], SCALE, bk);
          float p = __expf(t - m[rr]) * rl[rr];
          __builtin_nontemporal_store(
              p, &arow[(size_t)(q0 + 4 * g + rr) * SS + k0 + l16]);
          at[w][4 * g + rr][ks * 32 + kt * 16 + l16] = f2bf(p);
        }
      }
      short8 pa = *(const short8*)&at[w][l16][ks * 32 + 8 * g];
      short8 b0 = *(const short8*)&vt[l16][ks * 32 + 8 * g];
      short8 b1 = *(const short8*)&vt[16 + l16][ks * 32 + 8 * g];
      acc0 = __builtin_amdgcn_mfma_f32_16x16x32_bf16(pa, b0, acc0, 0, 0, 0);
      acc1 = __builtin_amdgcn_mfma_f32_16x16x32_bf16(pa, b1, acc1, 0, 0, 0);
    }
  }

#pragma unroll
  for (int rr = 0; rr < 4; ++rr) {
    int s = q0 + 4 * g + rr;
    size_t base = ((size_t)b * SS + s) * DMODEL + h * DD;
    concat[base + l16] = f2bf(acc0[rr]);
    concat[base + 16 + l16] = f2bf(acc1[rr]);
  }
}

// ---------- Kernel 3: out = concat @ Wo (fp32 out) ------------------------
__global__ __launch_bounds__(256) void outgemm_kernel(
    const unsigned short* __restrict__ concat,
    const unsigned short* __restrict__ wot,  // Wo^T bf16 [n][k]
    float* __restrict__ out) {
  int w = threadIdx.x >> 6, lane = threadIdx.x & 63, l16 = lane & 15,
      g = lane >> 4;
  int row = blockIdx.x * 64 + w * 16 + l16;
  int n0 = blockIdx.y * 64;
  float4_ z4 = {0.f, 0.f, 0.f, 0.f};
  float4_ acc[4] = {z4, z4, z4, z4};
  for (int k0 = 0; k0 < DMODEL; k0 += 32) {
    short8 a = *(const short8*)(concat + (size_t)row * DMODEL + k0 + 8 * g);
#pragma unroll
    for (int cb = 0; cb < 4; ++cb) {
      int n = n0 + cb * 16 + l16;
      short8 bfr = *(const short8*)(wot + (size_t)n * DMODEL + k0 + 8 * g);
      acc[cb] = __builtin_amdgcn_mfma_f32_16x16x32_bf16(a, bfr, acc[cb], 0, 0, 0);
    }
  }
  int rowbase = blockIdx.x * 64 + w * 16 + 4 * g;
#pragma unroll
  for (int cb = 0; cb < 4; ++cb)
#pragma unroll
    for (int rr = 0; rr < 4; ++rr)
      out[(size_t)(rowbase + rr) * DMODEL + n0 + cb * 16 + l16] = acc[cb][rr];
}

extern "C" void kernel_launch(void* const* d_in, const int* in_sizes, int n_in,
                              void* d_out, int out_size, void* d_ws,
                              size_t ws_size, hipStream_t stream) {
  const float* v = (const float*)d_in[0];
  const float* k = (const float*)d_in[1];
  const float* q = (const float*)d_in[2];
  const float* mask = (const float*)d_in[3];
  const float* Wq = (const float*)d_in[4];
  const float* Wk = (const float*)d_in[5];
  const float* Wv = (const float*)d_in[6];
  const float* Wo = (const float*)d_in[7];

  float* out = (float*)d_out;                    // [B,S,256]
  float* attn = out + (size_t)BB * SS * DMODEL;  // [B,H,S,S]

  const size_t NH = (size_t)BB * HH * SS * DD;  // 2,097,152
  unsigned short* qh = (unsigned short*)d_ws;
  unsigned short* kh = qh + NH;
  unsigned short* vh = kh + NH;
  unsigned short* concat = vh + NH;  // [B,S,256] bf16
  unsigned short* wt = concat + (size_t)BB * SS * DMODEL;  // 4x[256][256] bf16

  prep_w<<<dim3(8, 8, 4), 256, 0, stream>>>(Wq, Wk, Wv, Wo, wt);
  proj_kernel<<<dim3(128, 4, 3), 256, 0, stream>>>(q, k, v, wt, qh, kh, vh);
  fused_attn<<<dim3(32, 32), 256, 0, stream>>>(qh, kh, vh, mask, attn, concat);
  outgemm_kernel<<<dim3(128, 4), 256, 0, stream>>>(
      concat, wt + (size_t)3 * DMODEL * DMODEL, out);
}

// Round 5
// 262.714 us; speedup vs baseline: 1.0576x; 1.0576x over previous
//
#include <hip/hip_runtime.h>

#define BB 4
#define HH 8
#define SS 2048
#define DD 32
#define DMODEL 256
#define NEG_BIG_F (-1000000000.0f)
#define SCALE 0.17677669529663687f
#define L2E 1.4426950408889634f
#define SC2 (SCALE * L2E)

typedef short short8 __attribute__((ext_vector_type(8)));
typedef float float4_ __attribute__((ext_vector_type(4)));

__device__ __forceinline__ unsigned short f2bf(float x) {
  unsigned u = __float_as_uint(x);
  u += 0x7FFFu + ((u >> 16) & 1u);
  return (unsigned short)(u >> 16);
}

// ---------- Kernel 0: transpose+bf16 all weights: Wt[z][n][k] -------------
__global__ __launch_bounds__(256) void prep_w(
    const float* __restrict__ Wq, const float* __restrict__ Wk,
    const float* __restrict__ Wv, const float* __restrict__ Wo,
    unsigned short* __restrict__ wt) {
  __shared__ float tile[32][33];
  int z = blockIdx.z;
  const float* W = (z == 0) ? Wq : (z == 1) ? Wk : (z == 2) ? Wv : Wo;
  unsigned short* dst = wt + (size_t)z * DMODEL * DMODEL;
  int k0 = blockIdx.x * 32, n0 = blockIdx.y * 32;
  int tx = threadIdx.x & 31, ty = threadIdx.x >> 5;  // (32,8)
  for (int r = ty; r < 32; r += 8)
    tile[r][tx] = W[(size_t)(k0 + r) * DMODEL + n0 + tx];
  __syncthreads();
  for (int r = ty; r < 32; r += 8)
    dst[(size_t)(n0 + r) * DMODEL + k0 + tx] = f2bf(tile[tx][r]);
}

// ---------- Kernel 1: fused Q/K/V projections -> bf16, head-split ---------
__global__ __launch_bounds__(256) void proj_kernel(
    const float* __restrict__ q, const float* __restrict__ k,
    const float* __restrict__ v, const unsigned short* __restrict__ wt,
    unsigned short* __restrict__ qh, unsigned short* __restrict__ kh,
    unsigned short* __restrict__ vh) {
  int z = blockIdx.z;
  const float* src = (z == 0) ? q : (z == 1) ? k : v;
  const unsigned short* Wt = wt + (size_t)z * DMODEL * DMODEL;  // [n][k]
  unsigned short* dst = (z == 0) ? qh : (z == 1) ? kh : vh;

  int w = threadIdx.x >> 6, lane = threadIdx.x & 63, l16 = lane & 15,
      g = lane >> 4;
  int row = blockIdx.x * 64 + w * 16 + l16;
  int n0 = blockIdx.y * 64;

  float4_ z4 = {0.f, 0.f, 0.f, 0.f};
  float4_ acc[4] = {z4, z4, z4, z4};

  for (int k0 = 0; k0 < DMODEL; k0 += 32) {
    const float4_* ap = (const float4_*)(src + (size_t)row * DMODEL + k0 + 8 * g);
    float4_ a0 = ap[0], a1 = ap[1];
    short8 a;
#pragma unroll
    for (int j = 0; j < 4; ++j) {
      a[j] = (short)f2bf(a0[j]);
      a[4 + j] = (short)f2bf(a1[j]);
    }
#pragma unroll
    for (int cb = 0; cb < 4; ++cb) {
      int n = n0 + cb * 16 + l16;
      short8 bfr = *(const short8*)(Wt + (size_t)n * DMODEL + k0 + 8 * g);
      acc[cb] = __builtin_amdgcn_mfma_f32_16x16x32_bf16(a, bfr, acc[cb], 0, 0, 0);
    }
  }

  int rowbase = blockIdx.x * 64 + w * 16 + 4 * g;
#pragma unroll
  for (int cb = 0; cb < 4; ++cb) {
#pragma unroll
    for (int rr = 0; rr < 4; ++rr) {
      int r = rowbase + rr;
      int c = n0 + cb * 16 + l16;
      int b = r >> 11, s = r & (SS - 1);
      int h = c >> 5, d = c & 31;
      dst[(((size_t)(b * HH + h) * SS + s) * DD) + d] = f2bf(acc[cb][rr]);
    }
  }
}

// ---------- Kernel 2: fused stats + emit attn + PV ctx (swapped QK^T) -----
__global__ __launch_bounds__(256) void fused_attn(
    const unsigned short* __restrict__ qh, const unsigned short* __restrict__ kh,
    const unsigned short* __restrict__ vh, const float* __restrict__ mask,
    float* __restrict__ attn_out, unsigned short* __restrict__ concat) {
  __shared__ float biasl2[SS];              // (1-mask)*NEG_BIG*log2e
  __shared__ unsigned short vt[32][72];     // V^T tile, +8 pad
  __shared__ unsigned short at[4][16][72];  // per-wave P tile [16 q][64 k]+pad

  int bh = blockIdx.y;
  int b = bh >> 3, h = bh & 7;
  for (int i = threadIdx.x; i < SS; i += 256)
    biasl2[i] = (1.0f - mask[(size_t)b * SS + i]) * (NEG_BIG_F * L2E);
  __syncthreads();

  int w = threadIdx.x >> 6, lane = threadIdx.x & 63, l16 = lane & 15,
      g = lane >> 4;
  int q0 = blockIdx.x * 64 + w * 16;

  short8 qa = *(const short8*)(qh + ((size_t)bh * SS + q0 + l16) * DD + 8 * g);

  const unsigned short* kbase = kh + (size_t)bh * SS * DD;
  const unsigned short* vbase = vh + (size_t)bh * SS * DD;
  float4_ z4 = {0.f, 0.f, 0.f, 0.f};

  // ---- pass 1: per-lane online (m2, l) in exp2 domain; lane's q = q0+l16.
  // swapped mfma(K,Q): r[rr] = logit[k = k0+4g+rr][q = q0+l16]
  float m2 = -INFINITY, l = 0.f;
  for (int k0 = 0; k0 < SS; k0 += 32) {
#pragma unroll
    for (int kk = 0; kk < 2; ++kk) {
      int kt = k0 + kk * 16;
      short8 kf = *(const short8*)(kbase + (size_t)(kt + l16) * DD + 8 * g);
      float4_ r = __builtin_amdgcn_mfma_f32_16x16x32_bf16(kf, qa, z4, 0, 0, 0);
      float4_ b4 = *(const float4_*)&biasl2[kt + 4 * g];
      float t0 = fmaf(r[0], SC2, b4[0]);
      float t1 = fmaf(r[1], SC2, b4[1]);
      float t2 = fmaf(r[2], SC2, b4[2]);
      float t3 = fmaf(r[3], SC2, b4[3]);
      float nm = fmaxf(fmaxf(t0, t1), fmaxf(t2, t3));
      nm = fmaxf(nm, m2);
      float s = exp2f(m2 - nm);
      float e = exp2f(t0 - nm) + exp2f(t1 - nm) + exp2f(t2 - nm) +
                exp2f(t3 - nm);
      l = fmaf(l, s, e);
      m2 = nm;
    }
  }
  // merge across g-groups (lanes l16, l16+16, l16+32, l16+48 share q)
#pragma unroll
  for (int off = 16; off < 64; off <<= 1) {
    float om = __shfl_xor(m2, off);
    float ol = __shfl_xor(l, off);
    float nm = fmaxf(m2, om);
    l = l * exp2f(m2 - nm) + ol * exp2f(om - nm);
    m2 = nm;
  }
  float dq = m2 + log2f(l);  // p = exp2(t2 - dq)

  // ---- pass 2: emit normalized attn (float4 stores) + PV -----------------
  float* arow = attn_out + (size_t)bh * SS * SS + (size_t)(q0 + l16) * SS;
  float4_ acc0 = z4, acc1 = z4;

  int vr = threadIdx.x >> 2;         // 0..63: v-row in tile
  int dseg = (threadIdx.x & 3) * 8;  // d start

  for (int kb = 0; kb < SS; kb += 64) {
    __syncthreads();
    {  // stage V^T
      short8 vv = *(const short8*)(vbase + (size_t)(kb + vr) * DD + dseg);
#pragma unroll
      for (int j = 0; j < 8; ++j) vt[dseg + j][vr] = (unsigned short)vv[j];
    }
    __syncthreads();

#pragma unroll
    for (int ks = 0; ks < 2; ++ks) {
#pragma unroll
      for (int kt = 0; kt < 2; ++kt) {
        int kk0 = kb + ks * 32 + kt * 16;
        short8 kf = *(const short8*)(kbase + (size_t)(kk0 + l16) * DD + 8 * g);
        float4_ r = __builtin_amdgcn_mfma_f32_16x16x32_bf16(kf, qa, z4, 0, 0, 0);
        float4_ b4 = *(const float4_*)&biasl2[kk0 + 4 * g];
        float4_ p;
#pragma unroll
        for (int rr = 0; rr < 4; ++rr)
          p[rr] = exp2f(fmaf(r[rr], SC2, b4[rr] - dq));
        *(float4_*)(arow + kk0 + 4 * g) = p;  // 16B contiguous per lane
        unsigned u0 = ((unsigned)f2bf(p[1]) << 16) | f2bf(p[0]);
        unsigned u1 = ((unsigned)f2bf(p[3]) << 16) | f2bf(p[2]);
        uint2 pk;
        pk.x = u0;
        pk.y = u1;
        *(uint2*)&at[w][l16][ks * 32 + kt * 16 + 4 * g] = pk;  // ds_write_b64
      }
      short8 pa = *(const short8*)&at[w][l16][ks * 32 + 8 * g];
      short8 b0 = *(const short8*)&vt[l16][ks * 32 + 8 * g];
      short8 b1 = *(const short8*)&vt[16 + l16][ks * 32 + 8 * g];
      acc0 = __builtin_amdgcn_mfma_f32_16x16x32_bf16(pa, b0, acc0, 0, 0, 0);
      acc1 = __builtin_amdgcn_mfma_f32_16x16x32_bf16(pa, b1, acc1, 0, 0, 0);
    }
  }

#pragma unroll
  for (int rr = 0; rr < 4; ++rr) {
    int s = q0 + 4 * g + rr;
    size_t base = ((size_t)b * SS + s) * DMODEL + h * DD;
    concat[base + l16] = f2bf(acc0[rr]);
    concat[base + 16 + l16] = f2bf(acc1[rr]);
  }
}

// ---------- Kernel 3: out = concat @ Wo (fp32 out) ------------------------
__global__ __launch_bounds__(256) void outgemm_kernel(
    const unsigned short* __restrict__ concat,
    const unsigned short* __restrict__ wot,  // Wo^T bf16 [n][k]
    float* __restrict__ out) {
  int w = threadIdx.x >> 6, lane = threadIdx.x & 63, l16 = lane & 15,
      g = lane >> 4;
  int row = blockIdx.x * 64 + w * 16 + l16;
  int n0 = blockIdx.y * 64;
  float4_ z4 = {0.f, 0.f, 0.f, 0.f};
  float4_ acc[4] = {z4, z4, z4, z4};
  for (int k0 = 0; k0 < DMODEL; k0 += 32) {
    short8 a = *(const short8*)(concat + (size_t)row * DMODEL + k0 + 8 * g);
#pragma unroll
    for (int cb = 0; cb < 4; ++cb) {
      int n = n0 + cb * 16 + l16;
      short8 bfr = *(const short8*)(wot + (size_t)n * DMODEL + k0 + 8 * g);
      acc[cb] = __builtin_amdgcn_mfma_f32_16x16x32_bf16(a, bfr, acc[cb], 0, 0, 0);
    }
  }
  int rowbase = blockIdx.x * 64 + w * 16 + 4 * g;
#pragma unroll
  for (int cb = 0; cb < 4; ++cb)
#pragma unroll
    for (int rr = 0; rr < 4; ++rr)
      out[(size_t)(rowbase + rr) * DMODEL + n0 + cb * 16 + l16] = acc[cb][rr];
}

extern "C" void kernel_launch(void* const* d_in, const int* in_sizes, int n_in,
                              void* d_out, int out_size, void* d_ws,
                              size_t ws_size, hipStream_t stream) {
  const float* v = (const float*)d_in[0];
  const float* k = (const float*)d_in[1];
  const float* q = (const float*)d_in[2];
  const float* mask = (const float*)d_in[3];
  const float* Wq = (const float*)d_in[4];
  const float* Wk = (const float*)d_in[5];
  const float* Wv = (const float*)d_in[6];
  const float* Wo = (const float*)d_in[7];

  float* out = (float*)d_out;                    // [B,S,256]
  float* attn = out + (size_t)BB * SS * DMODEL;  // [B,H,S,S]

  const size_t NH = (size_t)BB * HH * SS * DD;  // 2,097,152
  unsigned short* qh = (unsigned short*)d_ws;
  unsigned short* kh = qh + NH;
  unsigned short* vh = kh + NH;
  unsigned short* concat = vh + NH;  // [B,S,256] bf16
  unsigned short* wt = concat + (size_t)BB * SS * DMODEL;  // 4x[256][256] bf16

  prep_w<<<dim3(8, 8, 4), 256, 0, stream>>>(Wq, Wk, Wv, Wo, wt);
  proj_kernel<<<dim3(128, 4, 3), 256, 0, stream>>>(q, k, v, wt, qh, kh, vh);
  fused_attn<<<dim3(32, 32), 256, 0, stream>>>(qh, kh, vh, mask, attn, concat);
  outgemm_kernel<<<dim3(128, 4), 256, 0, stream>>>(
      concat, wt + (size_t)3 * DMODEL * DMODEL, out);
}